// Round 5
// baseline (3167.722 us; speedup 1.0000x reference)
//
#include <hip/hip_runtime.h>

#define NB 16
#define NN 8192
#define NS 1024
#define NK 32
#define NR (NB*NS*NK)   // 524288 rows through the MLP

static __device__ __forceinline__ int brev6(int l) {
  return ((l&1)<<5)|((l&2)<<3)|((l&4)<<1)|((l&8)>>1)|((l&16)>>3)|((l&32)>>5);
}

// pack two f32 -> two bf16 (RNE) in one uint (low = first)
static __device__ __forceinline__ unsigned pack_bf2(float a, float b) {
  unsigned ua = __float_as_uint(a), ub = __float_as_uint(b);
  ua += 0x7fffu + ((ua >> 16) & 1u);
  ub += 0x7fffu + ((ub >> 16) & 1u);
  return (ua >> 16) | (ub & 0xffff0000u);
}
static __device__ __forceinline__ float bf_lo(unsigned u) { return __uint_as_float(u << 16); }
static __device__ __forceinline__ float bf_hi(unsigned u) { return __uint_as_float(u & 0xffff0000u); }

// ---------------------------------------------------------------------------
// FPS: one block (512 thr) per batch. Exact-order f32 distances (no fma,
// ascending sum = np reduce), first-index tie-break. PASSES — do not touch.
// ---------------------------------------------------------------------------
__global__ __launch_bounds__(512) void fps_kernel(const float* __restrict__ xyz,
                                                  float* __restrict__ new_xyz) {
  const int b = blockIdx.x;
  const int t = threadIdx.x;
  const int lane = t & 63;
  const int wv = t >> 6;
  const float* base = xyz + (size_t)b * NN * 3;

  float px[16], py[16], pz[16], dist[16];
#pragma unroll
  for (int j = 0; j < 16; ++j) {
    int p = j * 512 + t;
    px[j] = base[p*3+0]; py[j] = base[p*3+1]; pz[j] = base[p*3+2];
    dist[j] = 1e10f;
  }

  __shared__ unsigned long long s_wb[8];
  __shared__ float s_c[3];

  float cx = base[0], cy = base[1], cz = base[2];
  if (t == 0) {
    float* o = new_xyz + (size_t)b * NS * 3;
    o[0] = cx; o[1] = cy; o[2] = cz;
  }

  for (int s = 1; s < NS; ++s) {
    float bestv = -1.0f; int besti = 0;
#pragma unroll
    for (int j = 0; j < 16; ++j) {
      float dx = px[j]-cx, dy = py[j]-cy, dz = pz[j]-cz;
      float d = __fadd_rn(__fadd_rn(__fmul_rn(dx,dx),__fmul_rn(dy,dy)),__fmul_rn(dz,dz));
      float nd = fminf(dist[j], d);
      dist[j] = nd;
      if (nd > bestv) { bestv = nd; besti = j*512 + t; }
    }
    unsigned long long key =
        ((unsigned long long)__float_as_uint(bestv) << 32) | (unsigned)(8191 - besti);
#pragma unroll
    for (int off = 32; off >= 1; off >>= 1) {
      unsigned long long o2 = __shfl_xor(key, off, 64);
      if (o2 > key) key = o2;
    }
    if (lane == 0) s_wb[wv] = key;
    __syncthreads();
    key = s_wb[lane & 7];
#pragma unroll
    for (int off = 1; off <= 4; off <<= 1) {
      unsigned long long o2 = __shfl_xor(key, off, 64);
      if (o2 > key) key = o2;
    }
    const int bi = 8191 - (int)(key & 0xffffull);
    if (((bi ^ t) & 511) == 0) {
      const int jj = bi >> 9;
      float ncx = px[0], ncy = py[0], ncz = pz[0];
#pragma unroll
      for (int j = 1; j < 16; ++j) if (jj == j) { ncx = px[j]; ncy = py[j]; ncz = pz[j]; }
      s_c[0]=ncx; s_c[1]=ncy; s_c[2]=ncz;
      float* o = new_xyz + ((size_t)b * NS + s) * 3;
      o[0]=ncx; o[1]=ncy; o[2]=ncz;
    }
    __syncthreads();
    cx = s_c[0]; cy = s_c[1]; cz = s_c[2];
  }
}

// ---------------------------------------------------------------------------
// Ball query + gather + concat: one wave per (b,s) query.
// sq replicates a BLAS/Eigen-backed reference:
//   t1,t2: np.sum(x**2,-1) reduce = ascending ((x2+y2)+z2), no fma
//   dt:    sgemm K=3 microkernel = ascending FMA chain
//          fma(a2*b2, fma(a1*b1, a0*b0))  (each step single-rounded)
//   sq = (t1 - 2*dt) + t2 ; keep iff !(sq > f32(0.04))
// ---------------------------------------------------------------------------
__global__ __launch_bounds__(256) void ballquery_kernel(const float* __restrict__ xyz,
                                                        const float* __restrict__ pts,
                                                        const float* __restrict__ new_xyz,
                                                        float* __restrict__ x0) {
  const int gw = ((blockIdx.x << 8) + threadIdx.x) >> 6;
  const int lane = threadIdx.x & 63;
  const int b = gw >> 10;
  const float* base = xyz + (size_t)b * NN * 3;
  const float* pbase = pts + (size_t)b * NN * 3;
  const float* cp = new_xyz + (size_t)gw * 3;
  const float cx = cp[0], cy = cp[1], cz = cp[2];
  const float t1 = __fadd_rn(__fadd_rn(__fmul_rn(cx,cx),__fmul_rn(cy,cy)),__fmul_rn(cz,cz));
  const float R2 = 0.04f;   // f32(0.04) = 0.039999999105930328
  float* out = x0 + (size_t)gw * (NK*6);

  int count = 0, pfirst = 0;
  for (int n0 = 0; n0 < NN; n0 += 64) {
    const int p = n0 + lane;
    const float ax = base[p*3], ay = base[p*3+1], az = base[p*3+2];
    const float t2 = __fadd_rn(__fadd_rn(__fmul_rn(ax,ax),__fmul_rn(ay,ay)),__fmul_rn(az,az));
    // BLAS/Eigen K=3 dot: ascending FMA chain
    const float dt = __fmaf_rn(cz, az, __fmaf_rn(cy, ay, __fmul_rn(cx, ax)));
    const float sq = __fadd_rn(__fsub_rn(t1, __fmul_rn(2.0f,dt)), t2);
    const bool keep = !(sq > R2);
    const unsigned long long mask = __ballot(keep);
    const int slot = count + __popcll(mask & ((1ull<<lane)-1ull));
    if (keep && slot < NK) {
      float* o = out + slot*6;
      o[0]=ax-cx; o[1]=ay-cy; o[2]=az-cz;
      o[3]=pbase[p*3]; o[4]=pbase[p*3+1]; o[5]=pbase[p*3+2];
    }
    if (count == 0 && mask != 0ull) pfirst = n0 + (__ffsll((unsigned long long)mask) - 1);
    count += __popcll(mask);
    if (count >= NK) break;
  }
  if (count < NK) {
    const float* fx = base + (size_t)pfirst*3;
    const float* fp = pbase + (size_t)pfirst*3;
    const float a0 = fx[0]-cx, a1 = fx[1]-cy, a2 = fx[2]-cz;
    const float a3 = fp[0], a4 = fp[1], a5 = fp[2];
    for (int sl = count + lane; sl < NK; sl += 64) {
      float* o = out + sl*6;
      o[0]=a0;o[1]=a1;o[2]=a2;o[3]=a3;o[4]=a4;o[5]=a5;
    }
  }
}

// ---------------------------------------------------------------------------
// Wave transpose-reduce: lane ends with sum over 64 lanes of channel
// brev6(lane) in z[0]/q[0].
// ---------------------------------------------------------------------------
__device__ __forceinline__ void butterfly64(float (&z)[64], float (&q)[64], int lane) {
#pragma unroll
  for (int d = 0; d < 6; ++d) {
    const int m = 32 >> d;
    const bool hi = (lane >> d) & 1;
#pragma unroll
    for (int i = 0; i < m; ++i) {
      float sv = hi ? z[i] : z[i+m];
      float rv = __shfl_xor(sv, 1<<d, 64);
      z[i] = (hi ? z[i+m] : z[i]) + rv;
      float sq = hi ? q[i] : q[i+m];
      float rq = __shfl_xor(sq, 1<<d, 64);
      q[i] = (hi ? q[i+m] : q[i]) + rq;
    }
  }
}

// ---------------------------------------------------------------------------
// BN finalize: reduce per-wave partials in f64, emit scale/shift per channel.
// ---------------------------------------------------------------------------
__global__ __launch_bounds__(256) void finalize_kernel(const float* __restrict__ part,
                                                       int nrows, int rowstride, int C,
                                                       const float* __restrict__ g,
                                                       const float* __restrict__ be,
                                                       float* __restrict__ ab) {
  const int ch = blockIdx.x;
  const int t = threadIdx.x;
  const int qo = rowstride >> 1;
  double s = 0.0, q = 0.0;
  for (int wv = t; wv < nrows; wv += 256) {
    s += (double)part[(size_t)wv*rowstride + ch];
    q += (double)part[(size_t)wv*rowstride + qo + ch];
  }
#pragma unroll
  for (int off = 32; off >= 1; off >>= 1) {
    s += __shfl_down(s, off, 64);
    q += __shfl_down(q, off, 64);
  }
  __shared__ double ls[4], lq[4];
  if ((t & 63) == 0) { ls[t>>6] = s; lq[t>>6] = q; }
  __syncthreads();
  if (t == 0) {
    double S = ls[0]+ls[1]+ls[2]+ls[3];
    double Q = lq[0]+lq[1]+lq[2]+lq[3];
    double mean = S / (double)NR;
    double var  = Q / (double)NR - mean*mean;
    double inv  = 1.0 / sqrt(var + 1e-5);
    double gg   = (double)g[ch];
    ab[ch]     = (float)(gg * inv);
    ab[C + ch] = (float)((double)be[ch] - mean * gg * inv);
  }
}

// ============================ MID tier (bf16 z) ============================

__global__ __launch_bounds__(256) void mlp1_mid(const float* __restrict__ x0,
                                                const float* __restrict__ w,
                                                const float* __restrict__ bias,
                                                unsigned* __restrict__ z1u,
                                                float* __restrict__ part) {
  const int r = blockIdx.x * 256 + threadIdx.x;
  const int lane = threadIdx.x & 63;
  const float* xr = x0 + (size_t)r * 6;
  float x[6];
#pragma unroll
  for (int c = 0; c < 6; ++c) x[c] = xr[c];
  float z[64];
#pragma unroll
  for (int o = 0; o < 64; ++o) {
    float acc = bias[o];
#pragma unroll
    for (int c = 0; c < 6; ++c) acc = fmaf(x[c], w[o*6+c], acc);
    z[o] = acc;
  }
  uint4* zw = (uint4*)(z1u + (size_t)r * 32);
#pragma unroll
  for (int i = 0; i < 8; ++i)
    zw[i] = make_uint4(pack_bf2(z[8*i+0],z[8*i+1]), pack_bf2(z[8*i+2],z[8*i+3]),
                       pack_bf2(z[8*i+4],z[8*i+5]), pack_bf2(z[8*i+6],z[8*i+7]));
  float q[64];
#pragma unroll
  for (int o = 0; o < 64; ++o) q[o] = z[o]*z[o];
  butterfly64(z, q, lane);
  const int gw = (blockIdx.x * 256 + threadIdx.x) >> 6;
  const int ch = brev6(lane);
  part[(size_t)gw*128 + ch]      = z[0];
  part[(size_t)gw*128 + 64 + ch] = q[0];
}

__global__ __launch_bounds__(256) void mlp2_mid(const unsigned* __restrict__ z1u,
                                                const float* __restrict__ ab,
                                                const float* __restrict__ w,
                                                const float* __restrict__ bias,
                                                unsigned* __restrict__ z2u,
                                                float* __restrict__ part) {
  const int r = blockIdx.x * 256 + threadIdx.x;
  const int lane = threadIdx.x & 63;
  const uint4* zr = (const uint4*)(z1u + (size_t)r * 32);
  float x[64];
#pragma unroll
  for (int i = 0; i < 8; ++i) {
    uint4 v = zr[i];
    const int c = i*8;
    x[c+0]=fmaxf(0.f,fmaf(bf_lo(v.x),ab[c+0],ab[64+c+0]));
    x[c+1]=fmaxf(0.f,fmaf(bf_hi(v.x),ab[c+1],ab[64+c+1]));
    x[c+2]=fmaxf(0.f,fmaf(bf_lo(v.y),ab[c+2],ab[64+c+2]));
    x[c+3]=fmaxf(0.f,fmaf(bf_hi(v.y),ab[c+3],ab[64+c+3]));
    x[c+4]=fmaxf(0.f,fmaf(bf_lo(v.z),ab[c+4],ab[64+c+4]));
    x[c+5]=fmaxf(0.f,fmaf(bf_hi(v.z),ab[c+5],ab[64+c+5]));
    x[c+6]=fmaxf(0.f,fmaf(bf_lo(v.w),ab[c+6],ab[64+c+6]));
    x[c+7]=fmaxf(0.f,fmaf(bf_hi(v.w),ab[c+7],ab[64+c+7]));
  }
  float z[64];
#pragma unroll
  for (int o = 0; o < 64; ++o) {
    float acc = bias[o];
#pragma unroll
    for (int c = 0; c < 64; ++c) acc = fmaf(x[c], w[o*64+c], acc);
    z[o] = acc;
  }
  uint4* zw = (uint4*)(z2u + (size_t)r * 32);
#pragma unroll
  for (int i = 0; i < 8; ++i)
    zw[i] = make_uint4(pack_bf2(z[8*i+0],z[8*i+1]), pack_bf2(z[8*i+2],z[8*i+3]),
                       pack_bf2(z[8*i+4],z[8*i+5]), pack_bf2(z[8*i+6],z[8*i+7]));
  float q[64];
#pragma unroll
  for (int o = 0; o < 64; ++o) q[o] = z[o]*z[o];
  butterfly64(z, q, lane);
  const int gw = (blockIdx.x * 256 + threadIdx.x) >> 6;
  const int ch = brev6(lane);
  part[(size_t)gw*128 + ch]      = z[0];
  part[(size_t)gw*128 + 64 + ch] = q[0];
}

__global__ __launch_bounds__(256) void mlp3_mid(const unsigned* __restrict__ z2u,
                                                const float* __restrict__ ab,
                                                const float* __restrict__ w,
                                                const float* __restrict__ bias,
                                                unsigned* __restrict__ z3u,
                                                float* __restrict__ part) {
  const int r = blockIdx.x * 256 + threadIdx.x;
  const int lane = threadIdx.x & 63;
  const uint4* zr = (const uint4*)(z2u + (size_t)r * 32);
  float h[64];
#pragma unroll
  for (int i = 0; i < 8; ++i) {
    uint4 v = zr[i];
    const int c = i*8;
    h[c+0]=fmaxf(0.f,fmaf(bf_lo(v.x),ab[c+0],ab[64+c+0]));
    h[c+1]=fmaxf(0.f,fmaf(bf_hi(v.x),ab[c+1],ab[64+c+1]));
    h[c+2]=fmaxf(0.f,fmaf(bf_lo(v.y),ab[c+2],ab[64+c+2]));
    h[c+3]=fmaxf(0.f,fmaf(bf_hi(v.y),ab[c+3],ab[64+c+3]));
    h[c+4]=fmaxf(0.f,fmaf(bf_lo(v.z),ab[c+4],ab[64+c+4]));
    h[c+5]=fmaxf(0.f,fmaf(bf_hi(v.z),ab[c+5],ab[64+c+5]));
    h[c+6]=fmaxf(0.f,fmaf(bf_lo(v.w),ab[c+6],ab[64+c+6]));
    h[c+7]=fmaxf(0.f,fmaf(bf_hi(v.w),ab[c+7],ab[64+c+7]));
  }
  const int gw = (blockIdx.x * 256 + threadIdx.x) >> 6;
  const int ch = brev6(lane);
#pragma unroll
  for (int chunk = 0; chunk < 2; ++chunk) {
    float z[64];
#pragma unroll
    for (int o = 0; o < 64; ++o) {
      float acc = bias[chunk*64+o];
#pragma unroll
      for (int c = 0; c < 64; ++c) acc = fmaf(h[c], w[(chunk*64+o)*64+c], acc);
      z[o] = acc;
    }
    uint4* zw = (uint4*)(z3u + (size_t)r * 64 + chunk*32);
#pragma unroll
    for (int i = 0; i < 8; ++i)
      zw[i] = make_uint4(pack_bf2(z[8*i+0],z[8*i+1]), pack_bf2(z[8*i+2],z[8*i+3]),
                         pack_bf2(z[8*i+4],z[8*i+5]), pack_bf2(z[8*i+6],z[8*i+7]));
    float q[64];
#pragma unroll
    for (int o = 0; o < 64; ++o) q[o] = z[o]*z[o];
    butterfly64(z, q, lane);
    part[(size_t)gw*256 + chunk*64 + ch]       = z[0];
    part[(size_t)gw*256 + 128 + chunk*64 + ch] = q[0];
  }
}

__global__ __launch_bounds__(64) void pool_mid(const unsigned* __restrict__ z3u,
                                               const float* __restrict__ ab,
                                               float* __restrict__ outp) {
  const int g = blockIdx.x;          // 0..16383
  const int j = threadIdx.x;         // 0..63, owns channels 2j,2j+1
  const float sc0 = ab[2*j],   sh0 = ab[128+2*j];
  const float sc1 = ab[2*j+1], sh1 = ab[128+2*j+1];
  const unsigned* col = z3u + (size_t)g * NK * 64 + j;
  float m0 = 0.f, m1 = 0.f;
#pragma unroll 4
  for (int k = 0; k < NK; ++k) {
    unsigned u = col[(size_t)k*64];
    m0 = fmaxf(m0, fmaf(bf_lo(u), sc0, sh0));
    m1 = fmaxf(m1, fmaf(bf_hi(u), sc1, sh1));
  }
  outp[(size_t)g*128 + 2*j]   = m0;
  outp[(size_t)g*128 + 2*j+1] = m1;
}

// ============================ LEAN tier (recompute) ============================

__global__ __launch_bounds__(256) void stats1_lean(const float* __restrict__ x0,
                                                   const float* __restrict__ w,
                                                   const float* __restrict__ bias,
                                                   float* __restrict__ part) {
  const int r = blockIdx.x * 256 + threadIdx.x;
  const int lane = threadIdx.x & 63;
  const float* xr = x0 + (size_t)r * 6;
  float x[6];
#pragma unroll
  for (int c = 0; c < 6; ++c) x[c] = xr[c];
  float z[64];
#pragma unroll
  for (int o = 0; o < 64; ++o) {
    float acc = bias[o];
#pragma unroll
    for (int c = 0; c < 6; ++c) acc = fmaf(x[c], w[o*6+c], acc);
    z[o] = acc;
  }
  float q[64];
#pragma unroll
  for (int o = 0; o < 64; ++o) q[o] = z[o]*z[o];
  butterfly64(z, q, lane);
  const int gw = (blockIdx.x * 256 + threadIdx.x) >> 6;
  const int ch = brev6(lane);
  part[(size_t)gw*128 + ch]      = z[0];
  part[(size_t)gw*128 + 64 + ch] = q[0];
}

__device__ __forceinline__ void lean_h1(const float* __restrict__ xr,
                                        const float* __restrict__ w1,
                                        const float* __restrict__ b1,
                                        const float* __restrict__ ab1,
                                        float (&h)[64]) {
  float x[6];
#pragma unroll
  for (int c = 0; c < 6; ++c) x[c] = xr[c];
#pragma unroll
  for (int o = 0; o < 64; ++o) {
    float acc = b1[o];
#pragma unroll
    for (int c = 0; c < 6; ++c) acc = fmaf(x[c], w1[o*6+c], acc);
    h[o] = fmaxf(0.f, fmaf(acc, ab1[o], ab1[64+o]));
  }
}

__global__ __launch_bounds__(256) void stats2_lean(const float* __restrict__ x0,
                                                   const float* __restrict__ w1,
                                                   const float* __restrict__ b1,
                                                   const float* __restrict__ ab1,
                                                   const float* __restrict__ w2,
                                                   const float* __restrict__ b2,
                                                   float* __restrict__ part) {
  const int r = blockIdx.x * 256 + threadIdx.x;
  const int lane = threadIdx.x & 63;
  float h[64];
  lean_h1(x0 + (size_t)r*6, w1, b1, ab1, h);
  float z[64];
#pragma unroll
  for (int o = 0; o < 64; ++o) {
    float acc = b2[o];
#pragma unroll
    for (int c = 0; c < 64; ++c) acc = fmaf(h[c], w2[o*64+c], acc);
    z[o] = acc;
  }
  float q[64];
#pragma unroll
  for (int o = 0; o < 64; ++o) q[o] = z[o]*z[o];
  butterfly64(z, q, lane);
  const int gw = (blockIdx.x * 256 + threadIdx.x) >> 6;
  const int ch = brev6(lane);
  part[(size_t)gw*128 + ch]      = z[0];
  part[(size_t)gw*128 + 64 + ch] = q[0];
}

__device__ __forceinline__ void lean_h2(const float* __restrict__ xr,
                                        const float* __restrict__ w1,
                                        const float* __restrict__ b1,
                                        const float* __restrict__ ab1,
                                        const float* __restrict__ w2,
                                        const float* __restrict__ b2,
                                        const float* __restrict__ ab2,
                                        float (&h)[64]) {
  float h1[64];
  lean_h1(xr, w1, b1, ab1, h1);
#pragma unroll
  for (int o = 0; o < 64; ++o) {
    float acc = b2[o];
#pragma unroll
    for (int c = 0; c < 64; ++c) acc = fmaf(h1[c], w2[o*64+c], acc);
    h[o] = acc;
  }
#pragma unroll
  for (int o = 0; o < 64; ++o) h[o] = fmaxf(0.f, fmaf(h[o], ab2[o], ab2[64+o]));
}

__global__ __launch_bounds__(256) void stats3_lean(const float* __restrict__ x0,
                                                   const float* __restrict__ w1,
                                                   const float* __restrict__ b1,
                                                   const float* __restrict__ ab1,
                                                   const float* __restrict__ w2,
                                                   const float* __restrict__ b2,
                                                   const float* __restrict__ ab2,
                                                   const float* __restrict__ w3,
                                                   const float* __restrict__ b3,
                                                   float* __restrict__ part) {
  const int r = blockIdx.x * 256 + threadIdx.x;
  const int lane = threadIdx.x & 63;
  float h[64];
  lean_h2(x0 + (size_t)r*6, w1, b1, ab1, w2, b2, ab2, h);
  const int gw = (blockIdx.x * 256 + threadIdx.x) >> 6;
  const int ch = brev6(lane);
#pragma unroll
  for (int chunk = 0; chunk < 2; ++chunk) {
    float z[64];
#pragma unroll
    for (int o = 0; o < 64; ++o) {
      float acc = b3[chunk*64+o];
#pragma unroll
      for (int c = 0; c < 64; ++c) acc = fmaf(h[c], w3[(chunk*64+o)*64+c], acc);
      z[o] = acc;
    }
    float q[64];
#pragma unroll
    for (int o = 0; o < 64; ++o) q[o] = z[o]*z[o];
    butterfly64(z, q, lane);
    part[(size_t)gw*256 + chunk*64 + ch]       = z[0];
    part[(size_t)gw*256 + 128 + chunk*64 + ch] = q[0];
  }
}

__global__ __launch_bounds__(256) void pool_lean(const float* __restrict__ x0,
                                                 const float* __restrict__ w1,
                                                 const float* __restrict__ b1,
                                                 const float* __restrict__ ab1,
                                                 const float* __restrict__ w2,
                                                 const float* __restrict__ b2,
                                                 const float* __restrict__ ab2,
                                                 const float* __restrict__ w3,
                                                 const float* __restrict__ b3,
                                                 const float* __restrict__ ab3,
                                                 float* __restrict__ outp) {
  const int r = blockIdx.x * 256 + threadIdx.x;
  const int lane = threadIdx.x & 63;
  float h[64];
  lean_h2(x0 + (size_t)r*6, w1, b1, ab1, w2, b2, ab2, h);
#pragma unroll
  for (int chunk = 0; chunk < 2; ++chunk) {
    float z[64];
#pragma unroll
    for (int o = 0; o < 64; ++o) {
      float acc = b3[chunk*64+o];
#pragma unroll
      for (int c = 0; c < 64; ++c) acc = fmaf(h[c], w3[(chunk*64+o)*64+c], acc);
      z[o] = fmaxf(0.f, fmaf(acc, ab3[chunk*64+o], ab3[128+chunk*64+o]));
    }
#pragma unroll
    for (int off = 1; off <= 16; off <<= 1) {
#pragma unroll
      for (int o = 0; o < 64; ++o) z[o] = fmaxf(z[o], __shfl_xor(z[o], off, 64));
    }
    if (lane == 0 || lane == 32) {
      const int group = ((r >> 6) << 1) + (lane >> 5);
      float4* op = (float4*)(outp + (size_t)group*128 + chunk*64);
#pragma unroll
      for (int i = 0; i < 16; ++i)
        op[i] = make_float4(z[4*i], z[4*i+1], z[4*i+2], z[4*i+3]);
    }
  }
}

// ============================ launcher ============================

extern "C" void kernel_launch(void* const* d_in, const int* in_sizes, int n_in,
                              void* d_out, int out_size, void* d_ws, size_t ws_size,
                              hipStream_t stream) {
  (void)in_sizes; (void)n_in; (void)out_size;
  const float* xyz = (const float*)d_in[0];
  const float* pts = (const float*)d_in[1];
  const float* w1  = (const float*)d_in[2];
  const float* b1  = (const float*)d_in[3];
  const float* g1  = (const float*)d_in[4];
  const float* be1 = (const float*)d_in[5];
  const float* w2  = (const float*)d_in[6];
  const float* b2  = (const float*)d_in[7];
  const float* g2  = (const float*)d_in[8];
  const float* be2 = (const float*)d_in[9];
  const float* w3  = (const float*)d_in[10];
  const float* b3  = (const float*)d_in[11];
  const float* g3  = (const float*)d_in[12];
  const float* be3 = (const float*)d_in[13];

  float* out = (float*)d_out;
  float* new_xyz    = out;
  float* new_points = out + NB*NS*3;

  // f32 workspace region: x0 (NR*6) + part (2M) + ab (512)
  float* ws = (float*)d_ws;
  float* x0   = ws;
  float* part = x0 + (size_t)NR*6;
  float* ab   = part + 2097152;
  float* ab1  = ab;
  float* ab2  = ab + 128;
  float* ab3  = ab + 256;
  const size_t f32_bytes = ((size_t)NR*6 + 2097152 + 512) * 4;   // 20,973,568
  // bf16 region (MID tier)
  unsigned* z1u = (unsigned*)((char*)d_ws + f32_bytes);
  unsigned* z2u = z1u + (size_t)NR*32;
  unsigned* z3u = z2u + (size_t)NR*32;
  const size_t mid_bytes = f32_bytes + (size_t)NR*128*4;         // 289,409,024

  const bool mid = (ws_size >= mid_bytes);

  hipLaunchKernelGGL(fps_kernel, dim3(NB), dim3(512), 0, stream, xyz, new_xyz);
  hipLaunchKernelGGL(ballquery_kernel, dim3(NB*NS/4), dim3(256), 0, stream, xyz, pts, new_xyz, x0);

  if (mid) {
    hipLaunchKernelGGL(mlp1_mid, dim3(NR/256), dim3(256), 0, stream, x0, w1, b1, z1u, part);
    hipLaunchKernelGGL(finalize_kernel, dim3(64), dim3(256), 0, stream, part, NR/64, 128, 64, g1, be1, ab1);
    hipLaunchKernelGGL(mlp2_mid, dim3(NR/256), dim3(256), 0, stream, z1u, ab1, w2, b2, z2u, part);
    hipLaunchKernelGGL(finalize_kernel, dim3(64), dim3(256), 0, stream, part, NR/64, 128, 64, g2, be2, ab2);
    hipLaunchKernelGGL(mlp3_mid, dim3(NR/256), dim3(256), 0, stream, z2u, ab2, w3, b3, z3u, part);
    hipLaunchKernelGGL(finalize_kernel, dim3(128), dim3(256), 0, stream, part, NR/64, 256, 128, g3, be3, ab3);
    hipLaunchKernelGGL(pool_mid, dim3(NB*NS), dim3(64), 0, stream, z3u, ab3, new_points);
  } else {
    hipLaunchKernelGGL(stats1_lean, dim3(NR/256), dim3(256), 0, stream, x0, w1, b1, part);
    hipLaunchKernelGGL(finalize_kernel, dim3(64), dim3(256), 0, stream, part, NR/64, 128, 64, g1, be1, ab1);
    hipLaunchKernelGGL(stats2_lean, dim3(NR/256), dim3(256), 0, stream, x0, w1, b1, ab1, w2, b2, part);
    hipLaunchKernelGGL(finalize_kernel, dim3(64), dim3(256), 0, stream, part, NR/64, 128, 64, g2, be2, ab2);
    hipLaunchKernelGGL(stats3_lean, dim3(NR/256), dim3(256), 0, stream, x0, w1, b1, ab1, w2, b2, ab2, w3, b3, part);
    hipLaunchKernelGGL(finalize_kernel, dim3(128), dim3(256), 0, stream, part, NR/64, 256, 128, g3, be3, ab3);
    hipLaunchKernelGGL(pool_lean, dim3(NR/256), dim3(256), 0, stream, x0, w1, b1, ab1, w2, b2, ab2, w3, b3, ab3, new_points);
  }
}

// Round 6
// 2307.793 us; speedup vs baseline: 1.3726x; 1.3726x over previous
//
#include <hip/hip_runtime.h>

#define NB 16
#define NN 8192
#define NS 1024
#define NK 32
#define NR (NB*NS*NK)   // 524288 rows through the MLP

static __device__ __forceinline__ int brev6(int l) {
  return ((l&1)<<5)|((l&2)<<3)|((l&4)<<1)|((l&8)>>1)|((l&16)>>3)|((l&32)>>5);
}

// pack two f32 -> two bf16 (RNE) in one uint (low = first)
static __device__ __forceinline__ unsigned pack_bf2(float a, float b) {
  unsigned ua = __float_as_uint(a), ub = __float_as_uint(b);
  ua += 0x7fffu + ((ua >> 16) & 1u);
  ub += 0x7fffu + ((ub >> 16) & 1u);
  return (ua >> 16) | (ub & 0xffff0000u);
}
static __device__ __forceinline__ float bf_lo(unsigned u) { return __uint_as_float(u << 16); }
static __device__ __forceinline__ float bf_hi(unsigned u) { return __uint_as_float(u & 0xffff0000u); }

// ---------------------------------------------------------------------------
// FPS v2: one block (256 thr = 4 waves, 1/SIMD) per batch, 32 pts/thread.
// Same exact arithmetic + first-index tie-break as the passing version.
// ONE barrier per step: per-wave best keys go to parity-double-buffered LDS;
// every thread reduces the 4 keys itself and re-reads winner coords from
// global (broadcast, L1/L2-hot) — no owner-select chain, no 2nd barrier.
// ---------------------------------------------------------------------------
__global__ __launch_bounds__(256, 1) void fps_kernel(const float* __restrict__ xyz,
                                                     float* __restrict__ new_xyz) {
  const int b = blockIdx.x;
  const int t = threadIdx.x;        // 0..255
  const int lane = t & 63;
  const int wv = t >> 6;            // 0..3
  const float* base = xyz + (size_t)b * NN * 3;

  float px[32], py[32], pz[32], dist[32];
#pragma unroll
  for (int j = 0; j < 32; ++j) {
    int p = j * 256 + t;
    px[j] = base[p*3+0]; py[j] = base[p*3+1]; pz[j] = base[p*3+2];
    dist[j] = 1e10f;
  }

  __shared__ unsigned long long s_wb[2][4];   // [parity][wave]

  float cx = base[0], cy = base[1], cz = base[2];
  float* outp = new_xyz + (size_t)b * NS * 3;
  if (t == 0) { outp[0] = cx; outp[1] = cy; outp[2] = cz; }

  for (int s = 1; s < NS; ++s) {
    const int par = s & 1;
    float bestv = -1.0f; int besti = 0;
#pragma unroll
    for (int j = 0; j < 32; ++j) {
      float dx = px[j]-cx, dy = py[j]-cy, dz = pz[j]-cz;
      // exact numpy order: (dx*dx + dy*dy) + dz*dz, no contraction
      float d = __fadd_rn(__fadd_rn(__fmul_rn(dx,dx),__fmul_rn(dy,dy)),__fmul_rn(dz,dz));
      float nd = fminf(dist[j], d);
      dist[j] = nd;
      if (nd > bestv) { bestv = nd; besti = j*256 + t; }
    }
    // key: larger dist wins; on tie, smaller index wins (8191-idx larger)
    unsigned long long key =
        ((unsigned long long)__float_as_uint(bestv) << 32) | (unsigned)(8191 - besti);
#pragma unroll
    for (int off = 32; off >= 1; off >>= 1) {
      unsigned long long o2 = __shfl_xor(key, off, 64);
      if (o2 > key) key = o2;
    }
    if (lane == 0) s_wb[par][wv] = key;
    __syncthreads();                           // the only barrier per step
    unsigned long long gk = s_wb[par][0];
    {
      unsigned long long k1 = s_wb[par][1]; if (k1 > gk) gk = k1;
      unsigned long long k2 = s_wb[par][2]; if (k2 > gk) gk = k2;
      unsigned long long k3 = s_wb[par][3]; if (k3 > gk) gk = k3;
    }
    const int bi = 8191 - (int)(gk & 0xffffull);
    const float* cp = base + (size_t)bi * 3;   // broadcast load, cache-hot
    cx = cp[0]; cy = cp[1]; cz = cp[2];
    if (t == 0) {
      float* o = outp + s*3;
      o[0] = cx; o[1] = cy; o[2] = cz;
    }
  }
}

// ---------------------------------------------------------------------------
// Ball query + gather + concat: one wave per (b,s) query. PASSES — unchanged.
// dt = ascending FMA chain (BLAS K=3 microkernel), t1/t2 ascending no-fma.
// ---------------------------------------------------------------------------
__global__ __launch_bounds__(256) void ballquery_kernel(const float* __restrict__ xyz,
                                                        const float* __restrict__ pts,
                                                        const float* __restrict__ new_xyz,
                                                        float* __restrict__ x0) {
  const int gw = ((blockIdx.x << 8) + threadIdx.x) >> 6;
  const int lane = threadIdx.x & 63;
  const int b = gw >> 10;
  const float* base = xyz + (size_t)b * NN * 3;
  const float* pbase = pts + (size_t)b * NN * 3;
  const float* cp = new_xyz + (size_t)gw * 3;
  const float cx = cp[0], cy = cp[1], cz = cp[2];
  const float t1 = __fadd_rn(__fadd_rn(__fmul_rn(cx,cx),__fmul_rn(cy,cy)),__fmul_rn(cz,cz));
  const float R2 = 0.04f;
  float* out = x0 + (size_t)gw * (NK*6);

  int count = 0, pfirst = 0;
  for (int n0 = 0; n0 < NN; n0 += 64) {
    const int p = n0 + lane;
    const float ax = base[p*3], ay = base[p*3+1], az = base[p*3+2];
    const float t2 = __fadd_rn(__fadd_rn(__fmul_rn(ax,ax),__fmul_rn(ay,ay)),__fmul_rn(az,az));
    const float dt = __fmaf_rn(cz, az, __fmaf_rn(cy, ay, __fmul_rn(cx, ax)));
    const float sq = __fadd_rn(__fsub_rn(t1, __fmul_rn(2.0f,dt)), t2);
    const bool keep = !(sq > R2);
    const unsigned long long mask = __ballot(keep);
    const int slot = count + __popcll(mask & ((1ull<<lane)-1ull));
    if (keep && slot < NK) {
      float* o = out + slot*6;
      o[0]=ax-cx; o[1]=ay-cy; o[2]=az-cz;
      o[3]=pbase[p*3]; o[4]=pbase[p*3+1]; o[5]=pbase[p*3+2];
    }
    if (count == 0 && mask != 0ull) pfirst = n0 + (__ffsll((unsigned long long)mask) - 1);
    count += __popcll(mask);
    if (count >= NK) break;
  }
  if (count < NK) {
    const float* fx = base + (size_t)pfirst*3;
    const float* fp = pbase + (size_t)pfirst*3;
    const float a0 = fx[0]-cx, a1 = fx[1]-cy, a2 = fx[2]-cz;
    const float a3 = fp[0], a4 = fp[1], a5 = fp[2];
    for (int sl = count + lane; sl < NK; sl += 64) {
      float* o = out + sl*6;
      o[0]=a0;o[1]=a1;o[2]=a2;o[3]=a3;o[4]=a4;o[5]=a5;
    }
  }
}

// ---------------------------------------------------------------------------
// Wave transpose-reduce: lane ends with sum over 64 lanes of channel
// brev6(lane) in z[0]/q[0].
// ---------------------------------------------------------------------------
__device__ __forceinline__ void butterfly64(float (&z)[64], float (&q)[64], int lane) {
#pragma unroll
  for (int d = 0; d < 6; ++d) {
    const int m = 32 >> d;
    const bool hi = (lane >> d) & 1;
#pragma unroll
    for (int i = 0; i < m; ++i) {
      float sv = hi ? z[i] : z[i+m];
      float rv = __shfl_xor(sv, 1<<d, 64);
      z[i] = (hi ? z[i+m] : z[i]) + rv;
      float sq = hi ? q[i] : q[i+m];
      float rq = __shfl_xor(sq, 1<<d, 64);
      q[i] = (hi ? q[i+m] : q[i]) + rq;
    }
  }
}

// ---------------------------------------------------------------------------
// BN finalize: reduce per-wave partials in f64, emit scale/shift per channel.
// ---------------------------------------------------------------------------
__global__ __launch_bounds__(256) void finalize_kernel(const float* __restrict__ part,
                                                       int nrows, int rowstride, int C,
                                                       const float* __restrict__ g,
                                                       const float* __restrict__ be,
                                                       float* __restrict__ ab) {
  const int ch = blockIdx.x;
  const int t = threadIdx.x;
  const int qo = rowstride >> 1;
  double s = 0.0, q = 0.0;
  for (int wv = t; wv < nrows; wv += 256) {
    s += (double)part[(size_t)wv*rowstride + ch];
    q += (double)part[(size_t)wv*rowstride + qo + ch];
  }
#pragma unroll
  for (int off = 32; off >= 1; off >>= 1) {
    s += __shfl_down(s, off, 64);
    q += __shfl_down(q, off, 64);
  }
  __shared__ double ls[4], lq[4];
  if ((t & 63) == 0) { ls[t>>6] = s; lq[t>>6] = q; }
  __syncthreads();
  if (t == 0) {
    double S = ls[0]+ls[1]+ls[2]+ls[3];
    double Q = lq[0]+lq[1]+lq[2]+lq[3];
    double mean = S / (double)NR;
    double var  = Q / (double)NR - mean*mean;
    double inv  = 1.0 / sqrt(var + 1e-5);
    double gg   = (double)g[ch];
    ab[ch]     = (float)(gg * inv);
    ab[C + ch] = (float)((double)be[ch] - mean * gg * inv);
  }
}

// ============================ MLP passes ============================

__global__ __launch_bounds__(256) void stats1_lean(const float* __restrict__ x0,
                                                   const float* __restrict__ w,
                                                   const float* __restrict__ bias,
                                                   float* __restrict__ part) {
  const int r = blockIdx.x * 256 + threadIdx.x;
  const int lane = threadIdx.x & 63;
  const float* xr = x0 + (size_t)r * 6;
  float x[6];
#pragma unroll
  for (int c = 0; c < 6; ++c) x[c] = xr[c];
  float z[64];
#pragma unroll
  for (int o = 0; o < 64; ++o) {
    float acc = bias[o];
#pragma unroll
    for (int c = 0; c < 6; ++c) acc = fmaf(x[c], w[o*6+c], acc);
    z[o] = acc;
  }
  float q[64];
#pragma unroll
  for (int o = 0; o < 64; ++o) q[o] = z[o]*z[o];
  butterfly64(z, q, lane);
  const int gw = (blockIdx.x * 256 + threadIdx.x) >> 6;
  const int ch = brev6(lane);
  part[(size_t)gw*128 + ch]      = z[0];
  part[(size_t)gw*128 + 64 + ch] = q[0];
}

__device__ __forceinline__ void lean_h1(const float* __restrict__ xr,
                                        const float* __restrict__ w1,
                                        const float* __restrict__ b1,
                                        const float* __restrict__ ab1,
                                        float (&h)[64]) {
  float x[6];
#pragma unroll
  for (int c = 0; c < 6; ++c) x[c] = xr[c];
#pragma unroll
  for (int o = 0; o < 64; ++o) {
    float acc = b1[o];
#pragma unroll
    for (int c = 0; c < 6; ++c) acc = fmaf(x[c], w1[o*6+c], acc);
    h[o] = fmaxf(0.f, fmaf(acc, ab1[o], ab1[64+o]));
  }
}

__global__ __launch_bounds__(256) void stats2_lean(const float* __restrict__ x0,
                                                   const float* __restrict__ w1,
                                                   const float* __restrict__ b1,
                                                   const float* __restrict__ ab1,
                                                   const float* __restrict__ w2,
                                                   const float* __restrict__ b2,
                                                   float* __restrict__ part) {
  const int r = blockIdx.x * 256 + threadIdx.x;
  const int lane = threadIdx.x & 63;
  float h[64];
  lean_h1(x0 + (size_t)r*6, w1, b1, ab1, h);
  float z[64];
#pragma unroll
  for (int o = 0; o < 64; ++o) {
    float acc = b2[o];
#pragma unroll
    for (int c = 0; c < 64; ++c) acc = fmaf(h[c], w2[o*64+c], acc);
    z[o] = acc;
  }
  float q[64];
#pragma unroll
  for (int o = 0; o < 64; ++o) q[o] = z[o]*z[o];
  butterfly64(z, q, lane);
  const int gw = (blockIdx.x * 256 + threadIdx.x) >> 6;
  const int ch = brev6(lane);
  part[(size_t)gw*128 + ch]      = z[0];
  part[(size_t)gw*128 + 64 + ch] = q[0];
}

__device__ __forceinline__ void lean_h2(const float* __restrict__ xr,
                                        const float* __restrict__ w1,
                                        const float* __restrict__ b1,
                                        const float* __restrict__ ab1,
                                        const float* __restrict__ w2,
                                        const float* __restrict__ b2,
                                        const float* __restrict__ ab2,
                                        float (&h)[64]) {
  float h1[64];
  lean_h1(xr, w1, b1, ab1, h1);
#pragma unroll
  for (int o = 0; o < 64; ++o) {
    float acc = b2[o];
#pragma unroll
    for (int c = 0; c < 64; ++c) acc = fmaf(h1[c], w2[o*64+c], acc);
    h[o] = acc;
  }
#pragma unroll
  for (int o = 0; o < 64; ++o) h[o] = fmaxf(0.f, fmaf(h[o], ab2[o], ab2[64+o]));
}

// Pass 3 with z3 store (tier A): stats + bf16 z3 to workspace.
__global__ __launch_bounds__(256) void stats3_store(const float* __restrict__ x0,
                                                    const float* __restrict__ w1,
                                                    const float* __restrict__ b1,
                                                    const float* __restrict__ ab1,
                                                    const float* __restrict__ w2,
                                                    const float* __restrict__ b2,
                                                    const float* __restrict__ ab2,
                                                    const float* __restrict__ w3,
                                                    const float* __restrict__ b3,
                                                    unsigned* __restrict__ z3u,
                                                    float* __restrict__ part) {
  const int r = blockIdx.x * 256 + threadIdx.x;
  const int lane = threadIdx.x & 63;
  float h[64];
  lean_h2(x0 + (size_t)r*6, w1, b1, ab1, w2, b2, ab2, h);
  const int gw = (blockIdx.x * 256 + threadIdx.x) >> 6;
  const int ch = brev6(lane);
#pragma unroll
  for (int chunk = 0; chunk < 2; ++chunk) {
    float z[64];
#pragma unroll
    for (int o = 0; o < 64; ++o) {
      float acc = b3[chunk*64+o];
#pragma unroll
      for (int c = 0; c < 64; ++c) acc = fmaf(h[c], w3[(chunk*64+o)*64+c], acc);
      z[o] = acc;
    }
    uint4* zw = (uint4*)(z3u + (size_t)r * 64 + chunk*32);
#pragma unroll
    for (int i = 0; i < 8; ++i)
      zw[i] = make_uint4(pack_bf2(z[8*i+0],z[8*i+1]), pack_bf2(z[8*i+2],z[8*i+3]),
                         pack_bf2(z[8*i+4],z[8*i+5]), pack_bf2(z[8*i+6],z[8*i+7]));
    float q[64];
#pragma unroll
    for (int o = 0; o < 64; ++o) q[o] = z[o]*z[o];
    butterfly64(z, q, lane);
    part[(size_t)gw*256 + chunk*64 + ch]       = z[0];
    part[(size_t)gw*256 + 128 + chunk*64 + ch] = q[0];
  }
}

// Tier A pool: read z3 bf16, affine3+relu, max over K.
__global__ __launch_bounds__(64) void pool_mid(const unsigned* __restrict__ z3u,
                                               const float* __restrict__ ab,
                                               float* __restrict__ outp) {
  const int g = blockIdx.x;          // 0..16383
  const int j = threadIdx.x;         // 0..63, owns channels 2j,2j+1
  const float sc0 = ab[2*j],   sh0 = ab[128+2*j];
  const float sc1 = ab[2*j+1], sh1 = ab[128+2*j+1];
  const unsigned* col = z3u + (size_t)g * NK * 64 + j;
  float m0 = 0.f, m1 = 0.f;
#pragma unroll 4
  for (int k = 0; k < NK; ++k) {
    unsigned u = col[(size_t)k*64];
    m0 = fmaxf(m0, fmaf(bf_lo(u), sc0, sh0));
    m1 = fmaxf(m1, fmaf(bf_hi(u), sc1, sh1));
  }
  outp[(size_t)g*128 + 2*j]   = m0;
  outp[(size_t)g*128 + 2*j+1] = m1;
}

// LEAN fallback pass 3 (stats only) + full-recompute pool.
__global__ __launch_bounds__(256) void stats3_lean(const float* __restrict__ x0,
                                                   const float* __restrict__ w1,
                                                   const float* __restrict__ b1,
                                                   const float* __restrict__ ab1,
                                                   const float* __restrict__ w2,
                                                   const float* __restrict__ b2,
                                                   const float* __restrict__ ab2,
                                                   const float* __restrict__ w3,
                                                   const float* __restrict__ b3,
                                                   float* __restrict__ part) {
  const int r = blockIdx.x * 256 + threadIdx.x;
  const int lane = threadIdx.x & 63;
  float h[64];
  lean_h2(x0 + (size_t)r*6, w1, b1, ab1, w2, b2, ab2, h);
  const int gw = (blockIdx.x * 256 + threadIdx.x) >> 6;
  const int ch = brev6(lane);
#pragma unroll
  for (int chunk = 0; chunk < 2; ++chunk) {
    float z[64];
#pragma unroll
    for (int o = 0; o < 64; ++o) {
      float acc = b3[chunk*64+o];
#pragma unroll
      for (int c = 0; c < 64; ++c) acc = fmaf(h[c], w3[(chunk*64+o)*64+c], acc);
      z[o] = acc;
    }
    float q[64];
#pragma unroll
    for (int o = 0; o < 64; ++o) q[o] = z[o]*z[o];
    butterfly64(z, q, lane);
    part[(size_t)gw*256 + chunk*64 + ch]       = z[0];
    part[(size_t)gw*256 + 128 + chunk*64 + ch] = q[0];
  }
}

__global__ __launch_bounds__(256) void pool_lean(const float* __restrict__ x0,
                                                 const float* __restrict__ w1,
                                                 const float* __restrict__ b1,
                                                 const float* __restrict__ ab1,
                                                 const float* __restrict__ w2,
                                                 const float* __restrict__ b2,
                                                 const float* __restrict__ ab2,
                                                 const float* __restrict__ w3,
                                                 const float* __restrict__ b3,
                                                 const float* __restrict__ ab3,
                                                 float* __restrict__ outp) {
  const int r = blockIdx.x * 256 + threadIdx.x;
  const int lane = threadIdx.x & 63;
  float h[64];
  lean_h2(x0 + (size_t)r*6, w1, b1, ab1, w2, b2, ab2, h);
#pragma unroll
  for (int chunk = 0; chunk < 2; ++chunk) {
    float z[64];
#pragma unroll
    for (int o = 0; o < 64; ++o) {
      float acc = b3[chunk*64+o];
#pragma unroll
      for (int c = 0; c < 64; ++c) acc = fmaf(h[c], w3[(chunk*64+o)*64+c], acc);
      z[o] = fmaxf(0.f, fmaf(acc, ab3[chunk*64+o], ab3[128+chunk*64+o]));
    }
#pragma unroll
    for (int off = 1; off <= 16; off <<= 1) {
#pragma unroll
      for (int o = 0; o < 64; ++o) z[o] = fmaxf(z[o], __shfl_xor(z[o], off, 64));
    }
    if (lane == 0 || lane == 32) {
      const int group = ((r >> 6) << 1) + (lane >> 5);
      float4* op = (float4*)(outp + (size_t)group*128 + chunk*64);
#pragma unroll
      for (int i = 0; i < 16; ++i)
        op[i] = make_float4(z[4*i], z[4*i+1], z[4*i+2], z[4*i+3]);
    }
  }
}

// ============================ launcher ============================

extern "C" void kernel_launch(void* const* d_in, const int* in_sizes, int n_in,
                              void* d_out, int out_size, void* d_ws, size_t ws_size,
                              hipStream_t stream) {
  (void)in_sizes; (void)n_in; (void)out_size;
  const float* xyz = (const float*)d_in[0];
  const float* pts = (const float*)d_in[1];
  const float* w1  = (const float*)d_in[2];
  const float* b1  = (const float*)d_in[3];
  const float* g1  = (const float*)d_in[4];
  const float* be1 = (const float*)d_in[5];
  const float* w2  = (const float*)d_in[6];
  const float* b2  = (const float*)d_in[7];
  const float* g2  = (const float*)d_in[8];
  const float* be2 = (const float*)d_in[9];
  const float* w3  = (const float*)d_in[10];
  const float* b3  = (const float*)d_in[11];
  const float* g3  = (const float*)d_in[12];
  const float* be3 = (const float*)d_in[13];

  float* out = (float*)d_out;
  float* new_xyz    = out;
  float* new_points = out + NB*NS*3;

  // f32 workspace region: x0 (NR*6) + part (2M) + ab (512)
  float* ws = (float*)d_ws;
  float* x0   = ws;
  float* part = x0 + (size_t)NR*6;
  float* ab   = part + 2097152;
  float* ab1  = ab;
  float* ab2  = ab + 128;
  float* ab3  = ab + 256;
  const size_t f32_bytes = ((size_t)NR*6 + 2097152 + 512) * 4;     // 20,973,568
  // tier A region: z3 bf16 only (NR*64 u32 = 134,217,728 B)
  unsigned* z3u = (unsigned*)((char*)d_ws + f32_bytes);
  const size_t tierA_bytes = f32_bytes + (size_t)NR*64*4;          // 155,191,296
  const bool tierA = (ws_size >= tierA_bytes);

  hipLaunchKernelGGL(fps_kernel, dim3(NB), dim3(256), 0, stream, xyz, new_xyz);
  hipLaunchKernelGGL(ballquery_kernel, dim3(NB*NS/4), dim3(256), 0, stream, xyz, pts, new_xyz, x0);

  hipLaunchKernelGGL(stats1_lean, dim3(NR/256), dim3(256), 0, stream, x0, w1, b1, part);
  hipLaunchKernelGGL(finalize_kernel, dim3(64), dim3(256), 0, stream, part, NR/64, 128, 64, g1, be1, ab1);
  hipLaunchKernelGGL(stats2_lean, dim3(NR/256), dim3(256), 0, stream, x0, w1, b1, ab1, w2, b2, part);
  hipLaunchKernelGGL(finalize_kernel, dim3(64), dim3(256), 0, stream, part, NR/64, 128, 64, g2, be2, ab2);

  if (tierA) {
    hipLaunchKernelGGL(stats3_store, dim3(NR/256), dim3(256), 0, stream,
                       x0, w1, b1, ab1, w2, b2, ab2, w3, b3, z3u, part);
    hipLaunchKernelGGL(finalize_kernel, dim3(128), dim3(256), 0, stream, part, NR/64, 256, 128, g3, be3, ab3);
    hipLaunchKernelGGL(pool_mid, dim3(NB*NS), dim3(64), 0, stream, z3u, ab3, new_points);
  } else {
    hipLaunchKernelGGL(stats3_lean, dim3(NR/256), dim3(256), 0, stream,
                       x0, w1, b1, ab1, w2, b2, ab2, w3, b3, part);
    hipLaunchKernelGGL(finalize_kernel, dim3(128), dim3(256), 0, stream, part, NR/64, 256, 128, g3, be3, ab3);
    hipLaunchKernelGGL(pool_lean, dim3(NR/256), dim3(256), 0, stream,
                       x0, w1, b1, ab1, w2, b2, ab2, w3, b3, ab3, new_points);
  }
}